// Round 1
// baseline (65.866 us; speedup 1.0000x reference)
//
#include <hip/hip_runtime.h>

// ============================================================================
// PC-DONN collapse:
//   All propagation kernels H = exp(i*kz*z) have |H| == 1 (kz real on this
//   grid), and the phase screens exp(i*phase) have unit modulus. FFT pairs
//   obey Parseval, so sum|field|^2 is EXACTLY invariant through the whole
//   chain. Hence:
//       out[b] = (1/M) * sum_p x_in[b,p]^2 * sum_m |T_m[p]|^2
//   with T_m = fftshift(IDFT2_unnormalized(C_m * sqrt(p_v + 1e-12))).
//   Only the M screen IFFTs are required; fftshift is index XOR 64 per axis.
// ============================================================================

struct cplx { float x, y; };
__device__ __forceinline__ cplx cadd(cplx a, cplx b){ return {a.x+b.x, a.y+b.y}; }
__device__ __forceinline__ cplx csub(cplx a, cplx b){ return {a.x-b.x, a.y-b.y}; }
__device__ __forceinline__ cplx cmul(cplx a, cplx b){ return {a.x*b.x - a.y*b.y, a.x*b.y + a.y*b.x}; }
__device__ __forceinline__ cplx cmuli(cplx a){ return {-a.y, a.x}; }   // * (+i): inverse-FFT sign

// ---- small inverse DFTs (unnormalized, e^{+2pi i nk/N}), natural in/out ----
__device__ __forceinline__ void idft4(cplx&A,cplx&B,cplx&C,cplx&D){
    cplx e0=cadd(A,C), e1=csub(A,C), o0=cadd(B,D), o1=csub(B,D);
    cplx i1 = cmuli(o1);
    A=cadd(e0,o0); B=cadd(e1,i1); C=csub(e0,o0); D=csub(e1,i1);
}
__device__ __forceinline__ void idft8(cplx a[8]){
    cplx e0=a[0],e1=a[2],e2=a[4],e3=a[6];
    cplx o0=a[1],o1=a[3],o2=a[5],o3=a[7];
    idft4(e0,e1,e2,e3); idft4(o0,o1,o2,o3);
    const float Ch = 0.70710678118654752f;
    cplx t1 = cmul(o1, cplx{ Ch, Ch});
    cplx t2 = cmuli(o2);
    cplx t3 = cmul(o3, cplx{-Ch, Ch});
    a[0]=cadd(e0,o0); a[4]=csub(e0,o0);
    a[1]=cadd(e1,t1); a[5]=csub(e1,t1);
    a[2]=cadd(e2,t2); a[6]=csub(e2,t2);
    a[3]=cadd(e3,t3); a[7]=csub(e3,t3);
}
__device__ __forceinline__ void idft16(cplx a[16]){
    cplx e[8]={a[0],a[2],a[4],a[6],a[8],a[10],a[12],a[14]};
    cplx o[8]={a[1],a[3],a[5],a[7],a[9],a[11],a[13],a[15]};
    idft8(e); idft8(o);
    const float Ch=0.70710678118654752f, c1=0.92387953251128674f, s1=0.38268343236508977f;
    const cplx w[8]={{1.f,0.f},{c1,s1},{Ch,Ch},{s1,c1},{0.f,1.f},{-s1,c1},{-Ch,Ch},{-c1,s1}};
    #pragma unroll
    for(int n=0;n<8;++n){ cplx t=cmul(o[n],w[n]); a[n]=cadd(e[n],t); a[n+8]=csub(e[n],t); }
}

#define LDSP 130   // padded row stride (cplx) -> row stride 1040 B == 4 banks mod 32

// K1: per-m 2D inverse DFT (unnormalized) of C*G, write |t|^2 to I[m].
// Four-step per 1D FFT-128: N1=16 (idft16 over k1) then twiddle then N2=8
// (idft8 over k2). Index sets are thread-local per step -> in-place, only
// inter-step barriers. 1024 threads: 8 threads per row (then per column).
__global__ __launch_bounds__(1024, 1)
void screens_kernel(const float* __restrict__ c_noise, float* __restrict__ I, int M)
{
    __shared__ cplx fld[128 * LDSP];
    __shared__ cplx tw[128];                  // W128^j = e^{+2pi i j/128}
    const int m   = blockIdx.x;
    const int tid = threadIdx.x;

    if (tid < 128) {
        float s, c;
        sincosf((float)tid * (float)(2.0 * M_PI / 128.0), &s, &c);
        tw[tid] = { c, s };
    }

    // ---- load C*G (G = sqrt(p_v + 1e-12)) ----
    const float DF = 976.5625f;                  // 1/(N*DX)
    const float Ac = 2.5132741228718345e-7f;     // 2*pi*L^2
    const float Bc = 7.8956835208714865e-7f;     // 2*pi^2*L^2
    #pragma unroll 4
    for (int it = 0; it < 16; ++it) {
        int idx = it*1024 + tid;
        int i = idx >> 7, j = idx & 127;
        float fi = (float)(((i+64)&127) - 64) * DF;
        float fj = (float)(((j+64)&127) - 64) * DF;
        float G  = sqrtf(Ac * expf(-Bc * (fi*fi + fj*fj)) + 1e-12f);
        float2 cv = ((const float2*)c_noise)[(size_t)m*16384 + idx];
        fld[i*LDSP + j] = { cv.x * G, cv.y * G };
    }
    __syncthreads();

    // ================= row pass (IDFT over column index) =================
    {   // Step A: per k2=t, idft16 over k1 at positions t+8*k1, twiddle, in-place
        const int r = tid >> 3, t = tid & 7;
        cplx* row = fld + r*LDSP;
        cplx a[16];
        #pragma unroll
        for (int k1 = 0; k1 < 16; ++k1) a[k1] = row[t + 8*k1];
        idft16(a);
        #pragma unroll
        for (int n1 = 0; n1 < 16; ++n1) row[t + 8*n1] = cmul(a[n1], tw[(n1*t) & 127]);
    }
    __syncthreads();
    {   // Step B: per n1 in {t,t+8}, idft8 over k2 at [8*n1 .. 8*n1+7] -> x[n1+16*n2]
        const int r = tid >> 3, t = tid & 7;
        cplx* row = fld + r*LDSP;
        cplx b0[8], b1[8];
        #pragma unroll
        for (int k2 = 0; k2 < 8; ++k2) { b0[k2] = row[8*t + k2]; b1[k2] = row[8*(t+8) + k2]; }
        idft8(b0); idft8(b1);
        __syncthreads();                       // all reads done before scattered writes
        #pragma unroll
        for (int n2 = 0; n2 < 8; ++n2) {
            row[ t      + 16*n2] = b0[n2];
            row[(t + 8) + 16*n2] = b1[n2];
        }
    }
    __syncthreads();

    // ================= column pass (IDFT over row index) =================
    {
        const int c = tid >> 3, t = tid & 7;
        cplx a[16];
        #pragma unroll
        for (int k1 = 0; k1 < 16; ++k1) a[k1] = fld[(t + 8*k1)*LDSP + c];
        idft16(a);
        #pragma unroll
        for (int n1 = 0; n1 < 16; ++n1) fld[(t + 8*n1)*LDSP + c] = cmul(a[n1], tw[(n1*t) & 127]);
    }
    __syncthreads();
    {
        const int c = tid >> 3, t = tid & 7;
        cplx b0[8], b1[8];
        #pragma unroll
        for (int k2 = 0; k2 < 8; ++k2) {
            b0[k2] = fld[(8*t      + k2)*LDSP + c];
            b1[k2] = fld[(8*(t+8)  + k2)*LDSP + c];
        }
        idft8(b0); idft8(b1);
        float* Im = I + (size_t)m * 16384;     // |t_m|^2 straight from registers
        #pragma unroll
        for (int n2 = 0; n2 < 8; ++n2) {
            Im[( t      + 16*n2)*128 + c] = b0[n2].x*b0[n2].x + b0[n2].y*b0[n2].y;
            Im[((t + 8) + 16*n2)*128 + c] = b1[n2].x*b1[n2].x + b1[n2].y*b1[n2].y;
        }
    }
}

// K2: W[p] = sum_m I[m][p]  (deterministic fixed-order sum)
__global__ void wsum_kernel(const float* __restrict__ I, float* __restrict__ W, int M)
{
    int p = blockIdx.x * blockDim.x + threadIdx.x;
    if (p >= 16384) return;
    float s = 0.f;
    for (int m = 0; m < M; ++m) s += I[(size_t)m*16384 + p];
    W[p] = s;
}

// K3: out[b] = (1/M) * sum_p x[b,p]^2 * W[p ^ 0x2040]   (0x2040 = fftshift XOR)
__global__ void out_kernel(const float* __restrict__ x, const float* __restrict__ W,
                           float* __restrict__ out, int M)
{
    const int b = blockIdx.x;
    float acc = 0.f;
    for (int k = threadIdx.x; k < 16384; k += 256) {
        float xv = x[(size_t)b*16384 + k];
        acc = fmaf(xv*xv, W[k ^ 8256], acc);
    }
    #pragma unroll
    for (int off = 32; off > 0; off >>= 1) acc += __shfl_down(acc, off);
    __shared__ float part[4];
    if ((threadIdx.x & 63) == 0) part[threadIdx.x >> 6] = acc;
    __syncthreads();
    if (threadIdx.x == 0) out[b] = (part[0]+part[1]+part[2]+part[3]) / (float)M;
}

extern "C" void kernel_launch(void* const* d_in, const int* in_sizes, int n_in,
                              void* d_out, int out_size, void* d_ws, size_t ws_size,
                              hipStream_t stream)
{
    (void)n_in; (void)ws_size;
    const float* x_in    = (const float*)d_in[0];
    // d_in[1] (phases) provably does not affect the output (|exp(i*phase)|=1).
    const float* c_noise = (const float*)d_in[2];

    const int M = in_sizes[2] / (128*128*2);   // 100
    const int B = out_size;                    // 32

    float* I = (float*)d_ws;                   // M * 16384 floats
    float* W = I + (size_t)M * 16384;          // 16384 floats

    screens_kernel<<<dim3(M),  dim3(1024), 0, stream>>>(c_noise, I, M);
    wsum_kernel  <<<dim3(64),  dim3(256),  0, stream>>>(I, W, M);
    out_kernel   <<<dim3(B),   dim3(256),  0, stream>>>(x_in, W, (float*)d_out, M);
}

// Round 2
// 49.851 us; speedup vs baseline: 1.3212x; 1.3212x over previous
//
#include <hip/hip_runtime.h>

// ============================================================================
// PC-DONN collapse (validated round 1, absmax 0.0):
//   |H|==1 and |exp(i*phase)|==1, FFT pairs obey Parseval => sum|field|^2 is
//   exactly invariant through the whole propagation chain. Hence
//       out[b] = (1/M) * sum_p x_in[b,p]^2 * sum_m |T_m[p]|^2
//   with T_m = fftshift(IDFT2_unnorm(C_m * G)), G = sqrt(p_v + 1e-12).
//
// Round 2: the fused per-m 2D FFT (100 blocks, 131 KiB LDS, 1 block/CU on
// 100/256 CUs) was latency/occupancy-bound at ~66 us for a ~3 us roofline
// problem. Split into row-pass + column-pass kernels (800 blocks each,
// 16.6 KiB LDS, 128 threads) with a transposed global intermediate:
//   KR: mid[m][c*128 + i] = rowFFT(C*G)          (LDS transpose, 128B stores)
//   KC: I[m][c*128 + r]   = |colFFT(mid)|^2      (fully coalesced)
//   K2: Wshift[(r^64)*128 + (c^64)] = sum_m I    (coalesced read, 64KB scatter)
//   K3: out[b] = (1/M) sum_k x4[k].^2 . Wshift4[k]
// ============================================================================

struct cplx { float x, y; };
__device__ __forceinline__ cplx cadd(cplx a, cplx b){ return {a.x+b.x, a.y+b.y}; }
__device__ __forceinline__ cplx csub(cplx a, cplx b){ return {a.x-b.x, a.y-b.y}; }
__device__ __forceinline__ cplx cmul(cplx a, cplx b){ return {a.x*b.x - a.y*b.y, a.x*b.y + a.y*b.x}; }
__device__ __forceinline__ cplx cmuli(cplx a){ return {-a.y, a.x}; }   // * (+i): inverse-FFT sign

// ---- small inverse DFTs (unnormalized, e^{+2pi i nk/N}), natural in/out ----
__device__ __forceinline__ void idft4(cplx&A,cplx&B,cplx&C,cplx&D){
    cplx e0=cadd(A,C), e1=csub(A,C), o0=cadd(B,D), o1=csub(B,D);
    cplx i1 = cmuli(o1);
    A=cadd(e0,o0); B=cadd(e1,i1); C=csub(e0,o0); D=csub(e1,i1);
}
__device__ __forceinline__ void idft8(cplx a[8]){
    cplx e0=a[0],e1=a[2],e2=a[4],e3=a[6];
    cplx o0=a[1],o1=a[3],o2=a[5],o3=a[7];
    idft4(e0,e1,e2,e3); idft4(o0,o1,o2,o3);
    const float Ch = 0.70710678118654752f;
    cplx t1 = cmul(o1, cplx{ Ch, Ch});
    cplx t2 = cmuli(o2);
    cplx t3 = cmul(o3, cplx{-Ch, Ch});
    a[0]=cadd(e0,o0); a[4]=csub(e0,o0);
    a[1]=cadd(e1,t1); a[5]=csub(e1,t1);
    a[2]=cadd(e2,t2); a[6]=csub(e2,t2);
    a[3]=cadd(e3,t3); a[7]=csub(e3,t3);
}
__device__ __forceinline__ void idft16(cplx a[16]){
    cplx e[8]={a[0],a[2],a[4],a[6],a[8],a[10],a[12],a[14]};
    cplx o[8]={a[1],a[3],a[5],a[7],a[9],a[11],a[13],a[15]};
    idft8(e); idft8(o);
    const float Ch=0.70710678118654752f, c1=0.92387953251128674f, s1=0.38268343236508977f;
    const cplx w[8]={{1.f,0.f},{c1,s1},{Ch,Ch},{s1,c1},{0.f,1.f},{-s1,c1},{-Ch,Ch},{-c1,s1}};
    #pragma unroll
    for(int n=0;n<8;++n){ cplx t=cmul(o[n],w[n]); a[n]=cadd(e[n],t); a[n+8]=csub(e[n],t); }
}

#define LDSP 130   // padded row stride (cplx)
#define NR   16    // rows per block

// Shared four-step body: in-place FFT-128 of NR rows sitting in fld.
// 128 threads: (r = tid>>3) row, (t = tid&7) sub-lane; thread-local index
// sets per step -> in-place with only inter-step barriers.
__device__ __forceinline__ void fft128_rows(cplx* fld, const cplx* tw, int tid)
{
    const int r = tid >> 3, t = tid & 7;
    cplx* row = fld + r * LDSP;
    {   // Step A: idft16 over k1 at positions t+8*k1, twiddle, in-place
        cplx a[16];
        #pragma unroll
        for (int k1 = 0; k1 < 16; ++k1) a[k1] = row[t + 8*k1];
        idft16(a);
        #pragma unroll
        for (int n1 = 0; n1 < 16; ++n1) row[t + 8*n1] = cmul(a[n1], tw[(n1*t) & 127]);
    }
    __syncthreads();
    {   // Step B: idft8 over k2 for n1 in {t, t+8} -> natural-order output
        cplx b0[8], b1[8];
        #pragma unroll
        for (int k2 = 0; k2 < 8; ++k2) { b0[k2] = row[8*t + k2]; b1[k2] = row[8*(t+8) + k2]; }
        idft8(b0); idft8(b1);
        __syncthreads();                       // all reads done before scattered writes
        #pragma unroll
        for (int n2 = 0; n2 < 8; ++n2) {
            row[ t      + 16*n2] = b0[n2];
            row[(t + 8) + 16*n2] = b1[n2];
        }
    }
    __syncthreads();
}

// KR: row FFTs of C*G; write transposed intermediate mid[m][c*128 + i].
__global__ __launch_bounds__(128)
void rowfft_kernel(const float* __restrict__ c_noise, float2* __restrict__ mid)
{
    __shared__ cplx fld[NR * LDSP];
    __shared__ cplx tw[128];
    const int m   = blockIdx.x;
    const int rb  = blockIdx.y * NR;
    const int tid = threadIdx.x;

    {   float s, c;
        sincosf((float)tid * (float)(2.0 * M_PI / 128.0), &s, &c);
        tw[tid] = { c, s };
    }

    const float DF = 976.5625f;                  // 1/(N*DX)
    const float Ac = 2.5132741228718345e-7f;     // 2*pi*L^2
    const float Bc = 7.8956835208714865e-7f;     // 2*pi^2*L^2
    #pragma unroll
    for (int it = 0; it < NR; ++it) {
        const int i = rb + it, j = tid;
        float fi = (float)(((i+64)&127) - 64) * DF;
        float fj = (float)(((j+64)&127) - 64) * DF;
        float G  = sqrtf(Ac * expf(-Bc * (fi*fi + fj*fj)) + 1e-12f);
        float2 cv = ((const float2*)c_noise)[(size_t)m*16384 + i*128 + j];
        fld[it*LDSP + j] = { cv.x * G, cv.y * G };
    }
    __syncthreads();

    fft128_rows(fld, tw, tid);

    // Transposed store: thread = column c; 16 consecutive i's = 128 B line.
    const int c = tid;
    float4* dst4 = (float4*)(mid + (size_t)m*16384 + (size_t)c*128 + rb);
    #pragma unroll
    for (int r2 = 0; r2 < NR/2; ++r2) {
        cplx v0 = fld[(2*r2  )*LDSP + c];
        cplx v1 = fld[(2*r2+1)*LDSP + c];
        dst4[r2] = { v0.x, v0.y, v1.x, v1.y };
    }
}

// KC: column FFTs (contiguous in transposed layout); write I[m][c*128 + r].
__global__ __launch_bounds__(128)
void colfft_kernel(const float2* __restrict__ mid, float* __restrict__ I)
{
    __shared__ cplx fld[NR * LDSP];
    __shared__ cplx tw[128];
    const int m   = blockIdx.x;
    const int cb  = blockIdx.y * NR;
    const int tid = threadIdx.x;

    {   float s, c;
        sincosf((float)tid * (float)(2.0 * M_PI / 128.0), &s, &c);
        tw[tid] = { c, s };
    }

    #pragma unroll
    for (int it = 0; it < NR; ++it) {
        float2 v = mid[(size_t)m*16384 + (size_t)(cb + it)*128 + tid];
        fld[it*LDSP + tid] = { v.x, v.y };
    }
    __syncthreads();

    fft128_rows(fld, tw, tid);

    float* Im = I + (size_t)m * 16384;
    #pragma unroll
    for (int it = 0; it < NR; ++it) {
        cplx v = fld[it*LDSP + tid];
        Im[(size_t)(cb + it)*128 + tid] = v.x*v.x + v.y*v.y;
    }
}

// K2: Wshift[(r^64)*128 + (c^64)] = sum_m I[m][c*128 + r]
// (folds the transpose + fftshift; coalesced 6.5MB read, 64KB scatter write)
__global__ __launch_bounds__(64)
void wsum_kernel(const float* __restrict__ I, float* __restrict__ Wsh, int M)
{
    const int q = blockIdx.x * 64 + threadIdx.x;   // q = c*128 + r
    float s = 0.f;
    for (int m = 0; m < M; ++m) s += I[(size_t)m*16384 + q];
    const int r = q & 127, c = q >> 7;
    Wsh[((r ^ 64) << 7) | (c ^ 64)] = s;
}

// K3: out[b] = (1/M) * sum_p x[b,p]^2 * Wshift[p]   (float4 loads)
__global__ __launch_bounds__(256)
void out_kernel(const float* __restrict__ x, const float* __restrict__ Wsh,
                float* __restrict__ out, int M)
{
    const int b = blockIdx.x;
    const float4* x4 = (const float4*)(x + (size_t)b * 16384);
    const float4* w4 = (const float4*)Wsh;
    float acc = 0.f;
    #pragma unroll 4
    for (int k = threadIdx.x; k < 4096; k += 256) {
        float4 xv = x4[k], wv = w4[k];
        acc = fmaf(xv.x*xv.x, wv.x, acc);
        acc = fmaf(xv.y*xv.y, wv.y, acc);
        acc = fmaf(xv.z*xv.z, wv.z, acc);
        acc = fmaf(xv.w*xv.w, wv.w, acc);
    }
    #pragma unroll
    for (int off = 32; off > 0; off >>= 1) acc += __shfl_down(acc, off);
    __shared__ float part[4];
    if ((threadIdx.x & 63) == 0) part[threadIdx.x >> 6] = acc;
    __syncthreads();
    if (threadIdx.x == 0) out[b] = (part[0]+part[1]+part[2]+part[3]) / (float)M;
}

extern "C" void kernel_launch(void* const* d_in, const int* in_sizes, int n_in,
                              void* d_out, int out_size, void* d_ws, size_t ws_size,
                              hipStream_t stream)
{
    (void)n_in; (void)ws_size;
    const float* x_in    = (const float*)d_in[0];
    // d_in[1] (phases) provably does not affect the output (|exp(i*phase)|=1).
    const float* c_noise = (const float*)d_in[2];

    const int M = in_sizes[2] / (128*128*2);   // 100
    const int B = out_size;                    // 32

    float2* mid = (float2*)d_ws;                                   // M*16384*8 B
    float*  I   = (float*)((char*)d_ws + (size_t)M*16384*8);       // M*16384*4 B
    float*  Wsh = I + (size_t)M*16384;                             // 16384*4 B

    rowfft_kernel<<<dim3(M, 8),   dim3(128), 0, stream>>>(c_noise, mid);
    colfft_kernel<<<dim3(M, 8),   dim3(128), 0, stream>>>(mid, I);
    wsum_kernel  <<<dim3(256),    dim3(64),  0, stream>>>(I, Wsh, M);
    out_kernel   <<<dim3(B),      dim3(256), 0, stream>>>(x_in, Wsh, (float*)d_out, M);
}